// Round 13
// baseline (287.547 us; speedup 1.0000x reference)
//
#include <hip/hip_runtime.h>

constexpr int G = 64;
constexpr int C = 16;
constexpr int NBATCH = 4;
constexpr int HID = 96;
constexpr int G3 = G * G * G; // 262144 = 2^18

typedef _Float16 h2    __attribute__((ext_vector_type(2)));
typedef _Float16 f16x4 __attribute__((ext_vector_type(4)));
typedef _Float16 f16x8 __attribute__((ext_vector_type(8)));
typedef float    f32x4 __attribute__((ext_vector_type(4)));

__device__ __forceinline__ f32x4 mfma16(f16x8 a, f16x8 b, f32x4 c) {
    return __builtin_amdgcn_mfma_f32_16x16x32_f16(a, b, c, 0, 0, 0);
}

// ---------------------------------------------------------------------------
// Pass 0: pack W1 (96x64) and W2 (16x96) into MFMA A-fragment order (f16).
// A-frag for mfma_f32_16x16x32_f16: lane l holds A[row = l%16][k = (l/16)*8+j],
// j=0..7 (16B contiguous per lane). (Layout verified by R11: absmax 0.03125.)
// ---------------------------------------------------------------------------
__global__ __launch_bounds__(256)
void nca_packw(const float* __restrict__ w1, const float* __restrict__ w2,
               _Float16* __restrict__ a1p, _Float16* __restrict__ a2p)
{
    const int i = blockIdx.x * 256 + threadIdx.x; // 0..6143
    {
        const int j = i & 7, lane = (i >> 3) & 63, f = i >> 9; // f = mt*2+kt
        const int mt = f >> 1, kt = f & 1;
        const int y = mt * 16 + (lane & 15);
        const int x = kt * 32 + ((lane >> 4) << 3) + j;
        a1p[i] = (_Float16)w1[y * 64 + x];
    }
    if (i < 3 * 512) {
        const int j = i & 7, lane = (i >> 3) & 63, kt2 = i >> 9;
        const int c = lane & 15;
        const int y = kt2 * 32 + ((lane >> 4) << 3) + j;
        a2p[i] = (_Float16)w2[c * HID + y];
    }
}

// ---------------------------------------------------------------------------
// Pass 1: perception + MFMA MLP.
//
// R13 = R12 structure (256-thread blocks, 8x8x4 tile, X/H panels aliasing
// the dead stencil tile) with the register cap REMOVED. R12's (256,3) bound
// capped VGPR at 84 and the spill detector fired (WRITE_SIZE 69632->335872
// KB, +260 B/thread scratch): the GEMM live set needs ~110+. Session law,
// both sides now measured: <=64 unreachable (R2 spills), <=85 unreachable
// (R12 spills), 110-128 is the floor -> 2 waves/SIMD. What we KEEP from
// R12 over R11: two independent 256-thread blocks per CU (LDS 2x36864 B
// fits) overlap each other's barrier/global-latency stalls, where R11's
// single 512-thread block idled the whole CU at every __syncthreads.
// Invariant: WRITE_SIZE must be 69632 KB (zero spill).
// ---------------------------------------------------------------------------
constexpr int SY = 12;            // halo row stride (floats)
constexpr int SZ = 120;           // halo plane stride (floats)
constexpr int TZ = 6;             // halo planes per block (4 voxels + 2)
constexpr int TILE_F = TZ * SZ;   // 720 floats per channel
constexpr int HALO_N = 600;       // 10*10*6 live halo elements
constexpr int XROW = 144;         // X-panel row stride (bytes)
constexpr int HROW = 80;          // H row stride (bytes)
constexpr int XWAVE = 64 * XROW;  // 9216 B per wave

__global__ __launch_bounds__(256)
void nca_update(const float* __restrict__ state, const float* __restrict__ rand_u,
                const _Float16* __restrict__ a1p, const float* __restrict__ b1,
                const _Float16* __restrict__ a2p,
                float* __restrict__ out, float* __restrict__ premask)
{
    // 4 waves x 9216 B = 36864 B. Stencil tile (8 ch x 720 f = 23040 B)
    // aliases the front; X/H panels take over after the post-stencil barrier.
    __shared__ __align__(16) char smem[4 * XWAVE];
    float (*tile)[TILE_F] = (float(*)[TILE_F])smem;

    const int tid = threadIdx.x;
    const int bid = blockIdx.x;
    const int bx = bid & 7, by = (bid >> 3) & 7, bz = (bid >> 6) & 15, n = bid >> 10;
    const int x0 = bx * 8, y0 = by * 8, z0 = bz * 4;
    const float* sb = state + (size_t)n * C * G3;

    // --- halo offsets: 600 elems / 256 threads -> 3 slots (3rd predicated) ---
    int vo0, s0i, vo1, s1i, vo2, s2i;
    {
        const int j = tid;
        const int lx = j % 10, t = j / 10, ly = t % 10, lz = t / 10;
        s0i = lz * SZ + ly * SY + lx;
        vo0 = min(max(z0 + lz - 1, 0), G - 1) * (G * G)
            + min(max(y0 + ly - 1, 0), G - 1) * G
            + min(max(x0 + lx - 1, 0), G - 1);
    }
    {
        const int j = tid + 256;
        const int lx = j % 10, t = j / 10, ly = t % 10, lz = t / 10;
        s1i = lz * SZ + ly * SY + lx;
        vo1 = min(max(z0 + lz - 1, 0), G - 1) * (G * G)
            + min(max(y0 + ly - 1, 0), G - 1) * G
            + min(max(x0 + lx - 1, 0), G - 1);
    }
    const bool wr2 = (tid + 512 < HALO_N);
    {
        const int j = min(tid + 512, HALO_N - 1);
        const int lx = j % 10, t = j / 10, ly = t % 10, lz = t / 10;
        s2i = lz * SZ + ly * SY + lx;
        vo2 = min(max(z0 + lz - 1, 0), G - 1) * (G * G)
            + min(max(y0 + ly - 1, 0), G - 1) * G
            + min(max(x0 + lx - 1, 0), G - 1);
    }

    const int lxl = (tid & 7) + 1, lyl = ((tid >> 3) & 7) + 1, lzl = (tid >> 6) + 1; // lzl 1..4
    const int gx = x0 + lxl - 1, gy = y0 + lyl - 1, gz = z0 + lzl - 1;
    const size_t vofs = (size_t)gz * (G * G) + (size_t)gy * G + gx;
    const int cbase = (lzl - 1) * SZ + (lyl - 1) * SY + (lxl - 1);

    // Packed perception features: h2 pp[j] = features (2j, 2j+1); feature
    // index x = k*16 + c (k: 0=ident, 1=sobel-z, 2=sobel-y, 3=sobel-x).
    h2 pp[32];
    float pf0 = 0.f, pf1 = 0.f, pf2 = 0.f, pf3 = 0.f; // even-channel carry
    float amax = -3.0e38f;

#pragma unroll
    for (int g = 0; g < 2; ++g) {
        const float* sg = sb + (size_t)(g * 8) * G3;

        if (g) __syncthreads(); // previous group's stencil reads done (WAR)

        // Bulk-load 8 channels (zero-spill pattern: nothing lives across).
#pragma unroll
        for (int c = 0; c < 8; ++c) {
            tile[c][s0i] = sg[(size_t)c * G3 + vo0];
            tile[c][s1i] = sg[(size_t)c * G3 + vo1];
            if (wr2) tile[c][s2i] = sg[(size_t)c * G3 + vo2];
        }
        __syncthreads();

#pragma unroll
        for (int c = 0; c < 8; ++c) {
            const int cg = g * 8 + c;
            const float* buf = tile[c];
            float P0 = 0.f, P2 = 0.f, U0 = 0.f, U2 = 0.f, V0 = 0.f, V2 = 0.f;
            float ctr = 0.f, mx = -3.0e38f;
#pragma unroll
            for (int dz = 0; dz < 3; ++dz) {
                const float gzw = (dz == 1) ? 2.f : 1.f;
#pragma unroll
                for (int dy = 0; dy < 3; ++dy) {
                    const float gyw = (dy == 1) ? 2.f : 1.f;
                    const float* r = buf + cbase + dz * SZ + dy * SY;
                    const float a0 = r[0], a1 = r[1], a2 = r[2];
                    const float rs = a0 + 2.f * a1 + a2;
                    if (dz == 0) P0 += gyw * rs;
                    if (dz == 2) P2 += gyw * rs;
                    if (dy == 0) U0 += gzw * rs;
                    if (dy == 2) U2 += gzw * rs;
                    V0 += gzw * gyw * a0;
                    V2 += gzw * gyw * a2;
                    if (dz == 1 && dy == 1) ctr = a1;
                    if (cg == 3) mx = fmaxf(mx, fmaxf(fmaxf(a0, a1), a2));
                }
            }
            if (cg == 3) amax = mx;

            const float f0 = ctr;
            const float f1 = (P0 - P2) * 0.0625f;
            const float f2 = (U0 - U2) * 0.0625f;
            const float f3 = (V0 - V2) * 0.0625f;

            if (cg & 1) {
                const int j = cg >> 1;
                h2 v;
                v.x = (_Float16)pf0; v.y = (_Float16)f0; pp[j]      = v;
                v.x = (_Float16)pf1; v.y = (_Float16)f1; pp[8 + j]  = v;
                v.x = (_Float16)pf2; v.y = (_Float16)f2; pp[16 + j] = v;
                v.x = (_Float16)pf3; v.y = (_Float16)f3; pp[24 + j] = v;
            } else {
                pf0 = f0; pf1 = f1; pf2 = f2; pf3 = f3;
            }
        }
    }

    // All waves finished reading the tile; X/H panels may now overwrite it.
    __syncthreads();

    // Pre-alive mask store (thread-own voxel; frees amax before GEMMs).
    premask[(size_t)n * G3 + vofs] = (amax > 0.1f) ? 1.f : 0.f;

    // =================== MFMA MLP (wave-private) ===================
    const int lane = tid & 63;
    const int w    = tid >> 6;       // wave = z-slice; gz_wave = z0 + w
    const int l15  = lane & 15;
    const int lg   = lane >> 4;      // lane group 0..3
    char* xw = smem + w * XWAVE;

    // --- write X-panel: row v = lane (this thread's voxel), 64 f16 ---
#pragma unroll
    for (int q = 0; q < 8; ++q) {
        uint4 t;
        t.x = __builtin_bit_cast(unsigned, pp[4 * q]);
        t.y = __builtin_bit_cast(unsigned, pp[4 * q + 1]);
        t.z = __builtin_bit_cast(unsigned, pp[4 * q + 2]);
        t.w = __builtin_bit_cast(unsigned, pp[4 * q + 3]);
        *(uint4*)(xw + lane * XROW + q * 16) = t;
    }

    // --- load B1 fragments (X^T): B[k][v], lane: k=lg*8+j, v=nt*16+l15 ---
    f16x8 bfr[8]; // [kt*4 + nt]
#pragma unroll
    for (int kt = 0; kt < 2; ++kt)
#pragma unroll
        for (int nt = 0; nt < 4; ++nt)
            bfr[kt * 4 + nt] = *(const f16x8*)(xw + (nt * 16 + l15) * XROW + kt * 64 + lg * 16);

    const f16x8* a1 = ((const f16x8*)a1p) + lane;
    const f16x8* a2 = ((const f16x8*)a2p) + lane;

    f32x4 acc2[4];
#pragma unroll
    for (int nt = 0; nt < 4; ++nt) acc2[nt] = (f32x4){0.f, 0.f, 0.f, 0.f};

    // --- interleaved GEMM1/GEMM2 per 32-row hidden block ---
    // (DS ops are per-wave in-order: H writes over the dead X region are
    //  safe after the bfr reads above have been issued.)
#pragma unroll 1
    for (int kt2 = 0; kt2 < 3; ++kt2) {
#pragma unroll
        for (int mtsub = 0; mtsub < 2; ++mtsub) {
            const int mt = kt2 * 2 + mtsub;
            const f16x8 a_0 = a1[(mt * 2 + 0) * 64];
            const f16x8 a_1 = a1[(mt * 2 + 1) * 64];
            const f32x4 bias = *(const f32x4*)(b1 + mt * 16 + lg * 4);
#pragma unroll
            for (int nt = 0; nt < 4; ++nt) {
                f32x4 acc = (f32x4){0.f, 0.f, 0.f, 0.f};
                acc = mfma16(a_0, bfr[nt],     acc);
                acc = mfma16(a_1, bfr[4 + nt], acc);
                // h = relu(acc + bias), rows y = mt*16 + lg*4 + r
                f16x4 hv;
                hv[0] = (_Float16)fmaxf(acc[0] + bias[0], 0.f);
                hv[1] = (_Float16)fmaxf(acc[1] + bias[1], 0.f);
                hv[2] = (_Float16)fmaxf(acc[2] + bias[2], 0.f);
                hv[3] = (_Float16)fmaxf(acc[3] + bias[3], 0.f);
                // H stored [v][y-local] (y-local = y - kt2*32, 32 per block)
                *(f16x4*)(xw + (nt * 16 + l15) * HROW + mtsub * 32 + lg * 8) = hv;
            }
        }
        // GEMM2 partial: delta^T += W2[:, kt2-block] @ H-block
        const f16x8 a2f = a2[kt2 * 64];
#pragma unroll
        for (int nt = 0; nt < 4; ++nt) {
            const f16x8 b2 = *(const f16x8*)(xw + (nt * 16 + l15) * HROW + lg * 16);
            acc2[nt] = mfma16(a2f, b2, acc2[nt]);
        }
    }

    // --- epilogue: lane holds delta for c = lg*4+r, v = nt*16+l15 ---
    float* ob = out + (size_t)n * C * G3;
#pragma unroll
    for (int nt = 0; nt < 4; ++nt) {
        const int vv = nt * 16 + l15;
        const int vx = vv & 7, vy = vv >> 3;
        const size_t vo = (size_t)(z0 + w) * (G * G) + (size_t)(y0 + vy) * G + (x0 + vx);
        const float ru = rand_u[(size_t)n * G3 + vo];
        const float m = (ru < 0.5f) ? 1.f : 0.f;
#pragma unroll
        for (int r = 0; r < 4; ++r) {
            const int c = lg * 4 + r;
            const float s0 = sb[(size_t)c * G3 + vo];
            ob[(size_t)c * G3 + vo] = fmaf(acc2[nt][r], m, s0);
        }
    }
}

// ---------------------------------------------------------------------------
// Pass 2a: post-alive pooling on the NEW alpha (read-only on d_out),
// combine with pre-alive mask in-place in d_ws. No cross-thread hazards.
// ---------------------------------------------------------------------------
__global__ __launch_bounds__(256)
void nca_postmask(const float* __restrict__ newstate, float* __restrict__ mask)
{
    const int idx = blockIdx.x * 256 + threadIdx.x; // over NBATCH*G3
    const int n = idx >> 18;
    const int v = idx & (G3 - 1);
    const int x = v & 63, y = (v >> 6) & 63, z = v >> 12;
    const float* ab = newstate + ((size_t)n * C + 3) * G3;
    float mx = -3.0e38f;
#pragma unroll
    for (int dz = -1; dz <= 1; ++dz) {
        const int zz = min(max(z + dz, 0), G - 1);
#pragma unroll
        for (int dy = -1; dy <= 1; ++dy) {
            const int yy = min(max(y + dy, 0), G - 1);
            const int xm = max(x - 1, 0), xp = min(x + 1, G - 1);
            const float* row = ab + (size_t)zz * (G * G) + (size_t)yy * G;
            mx = fmaxf(mx, fmaxf(fmaxf(row[xm], row[x]), row[xp]));
        }
    }
    const float post = (mx > 0.1f) ? 1.f : 0.f;
    mask[idx] *= post;
}

// ---------------------------------------------------------------------------
// Pass 2b: out *= mask (broadcast over channels), float4-vectorized.
// ---------------------------------------------------------------------------
__global__ __launch_bounds__(256)
void nca_apply(float4* __restrict__ out4, const float4* __restrict__ mask4)
{
    const int idx = blockIdx.x * 256 + threadIdx.x; // over NBATCH*C*G3/4
    const size_t base = (size_t)idx * 4;
    const int n = (int)(base >> 22);          // C*G3 = 2^22
    const int v = (int)(base & (G3 - 1));     // G3 = 2^18
    const float4 m = mask4[((size_t)n * G3 + v) >> 2];
    float4 o = out4[idx];
    o.x *= m.x; o.y *= m.y; o.z *= m.z; o.w *= m.w;
    out4[idx] = o;
}

extern "C" void kernel_launch(void* const* d_in, const int* in_sizes, int n_in,
                              void* d_out, int out_size, void* d_ws, size_t ws_size,
                              hipStream_t stream)
{
    const float* state  = (const float*)d_in[0];
    const float* rand_u = (const float*)d_in[1];
    const float* w1     = (const float*)d_in[2];
    const float* b1     = (const float*)d_in[3];
    const float* w2     = (const float*)d_in[4];
    float* out  = (float*)d_out;

    // Workspace: [0,12KB) a1p, [12KB,15KB) a2p, [16KB, 16KB+4MiB) mask.
    _Float16* a1p = (_Float16*)d_ws;
    _Float16* a2p = (_Float16*)((char*)d_ws + 12 * 1024);
    float*    mask = (float*)((char*)d_ws + 16 * 1024);

    nca_packw   <<<24, 256, 0, stream>>>(w1, w2, a1p, a2p);
    nca_update  <<<NBATCH * 8 * 8 * 16, 256, 0, stream>>>(state, rand_u, a1p, b1, a2p, out, mask);
    nca_postmask<<<(NBATCH * G3) / 256, 256, 0, stream>>>(out, mask);
    nca_apply   <<<(NBATCH * C * G3 / 4) / 256, 256, 0, stream>>>((float4*)out, (const float4*)mask);
}

// Round 14
// 177.784 us; speedup vs baseline: 1.6174x; 1.6174x over previous
//
#include <hip/hip_runtime.h>

constexpr int G = 64;
constexpr int C = 16;
constexpr int NBATCH = 4;
constexpr int HID = 96;
constexpr int G3 = G * G * G; // 262144 = 2^18

typedef _Float16 h2    __attribute__((ext_vector_type(2)));
typedef _Float16 f16x4 __attribute__((ext_vector_type(4)));
typedef _Float16 f16x8 __attribute__((ext_vector_type(8)));
typedef float    f32x4 __attribute__((ext_vector_type(4)));

__device__ __forceinline__ f32x4 mfma16(f16x8 a, f16x8 b, f32x4 c) {
    return __builtin_amdgcn_mfma_f32_16x16x32_f16(a, b, c, 0, 0, 0);
}

// ---------------------------------------------------------------------------
// Pass 0: pack W1 (96x64) and W2 (16x96) into MFMA A-fragment order (f16).
// A-frag for mfma_f32_16x16x32_f16: lane l holds A[row = l%16][k = (l/16)*8+j],
// j=0..7 (16B contiguous per lane). (Layout verified by R11: absmax 0.03125.)
// ---------------------------------------------------------------------------
__global__ __launch_bounds__(256)
void nca_packw(const float* __restrict__ w1, const float* __restrict__ w2,
               _Float16* __restrict__ a1p, _Float16* __restrict__ a2p)
{
    const int i = blockIdx.x * 256 + threadIdx.x; // 0..6143
    {
        const int j = i & 7, lane = (i >> 3) & 63, f = i >> 9; // f = mt*2+kt
        const int mt = f >> 1, kt = f & 1;
        const int y = mt * 16 + (lane & 15);
        const int x = kt * 32 + ((lane >> 4) << 3) + j;
        a1p[i] = (_Float16)w1[y * 64 + x];
    }
    if (i < 3 * 512) {
        const int j = i & 7, lane = (i >> 3) & 63, kt2 = i >> 9;
        const int c = lane & 15;
        const int y = kt2 * 32 + ((lane >> 4) << 3) + j;
        a2p[i] = (_Float16)w2[c * HID + y];
    }
}

// ---------------------------------------------------------------------------
// Pass 1: perception + MFMA MLP + pre-alive fold-in.
//
// R14: two changes over R13.
//  (1) __launch_bounds__(256, 2): R13 proved that without a min-waves hint
//      the allocator takes 144 VGPR -> 1 wave/SIMD (11.8% occ, 314 us).
//      The session law is waves/SIMD = floor(256/VGPR); the GEMM live set
//      is proven <=120 (R11's 512-thread build). (256,2) applies the same
//      128 cap R11 had implicitly, at 256-thread granularity -> 2 blocks/CU
//      with de-correlated barrier stalls. Invariant: WRITE_SIZE 69632 KB.
//  (2) pre-alive mask is folded into the update's own store (out =
//      new_state * pre, pre fetched cross-lane via __shfl since the GEMM
//      epilogue redistributes voxels over lanes), and the UNMASKED new
//      alpha goes to a 4 MiB side buffer for the tail pass. This lets the
//      tail skip all writes for alive voxels (see nca_post).
// ---------------------------------------------------------------------------
constexpr int SY = 12;            // halo row stride (floats)
constexpr int SZ = 120;           // halo plane stride (floats)
constexpr int TZ = 6;             // halo planes per block (4 voxels + 2)
constexpr int TILE_F = TZ * SZ;   // 720 floats per channel
constexpr int HALO_N = 600;       // 10*10*6 live halo elements
constexpr int XROW = 144;         // X-panel row stride (bytes)
constexpr int HROW = 80;          // H row stride (bytes)
constexpr int XWAVE = 64 * XROW;  // 9216 B per wave

__global__ __launch_bounds__(256, 2)
void nca_update(const float* __restrict__ state, const float* __restrict__ rand_u,
                const _Float16* __restrict__ a1p, const float* __restrict__ b1,
                const _Float16* __restrict__ a2p,
                float* __restrict__ out, float* __restrict__ acopy)
{
    // 4 waves x 9216 B = 36864 B. Stencil tile (8 ch x 720 f = 23040 B)
    // aliases the front; X/H panels take over after the post-stencil barrier.
    __shared__ __align__(16) char smem[4 * XWAVE];
    float (*tile)[TILE_F] = (float(*)[TILE_F])smem;

    const int tid = threadIdx.x;
    const int bid = blockIdx.x;
    const int bx = bid & 7, by = (bid >> 3) & 7, bz = (bid >> 6) & 15, n = bid >> 10;
    const int x0 = bx * 8, y0 = by * 8, z0 = bz * 4;
    const float* sb = state + (size_t)n * C * G3;

    // --- halo offsets: 600 elems / 256 threads -> 3 slots (3rd predicated) ---
    int vo0, s0i, vo1, s1i, vo2, s2i;
    {
        const int j = tid;
        const int lx = j % 10, t = j / 10, ly = t % 10, lz = t / 10;
        s0i = lz * SZ + ly * SY + lx;
        vo0 = min(max(z0 + lz - 1, 0), G - 1) * (G * G)
            + min(max(y0 + ly - 1, 0), G - 1) * G
            + min(max(x0 + lx - 1, 0), G - 1);
    }
    {
        const int j = tid + 256;
        const int lx = j % 10, t = j / 10, ly = t % 10, lz = t / 10;
        s1i = lz * SZ + ly * SY + lx;
        vo1 = min(max(z0 + lz - 1, 0), G - 1) * (G * G)
            + min(max(y0 + ly - 1, 0), G - 1) * G
            + min(max(x0 + lx - 1, 0), G - 1);
    }
    const bool wr2 = (tid + 512 < HALO_N);
    {
        const int j = min(tid + 512, HALO_N - 1);
        const int lx = j % 10, t = j / 10, ly = t % 10, lz = t / 10;
        s2i = lz * SZ + ly * SY + lx;
        vo2 = min(max(z0 + lz - 1, 0), G - 1) * (G * G)
            + min(max(y0 + ly - 1, 0), G - 1) * G
            + min(max(x0 + lx - 1, 0), G - 1);
    }

    const int lxl = (tid & 7) + 1, lyl = ((tid >> 3) & 7) + 1, lzl = (tid >> 6) + 1; // lzl 1..4
    const int cbase = (lzl - 1) * SZ + (lyl - 1) * SY + (lxl - 1);

    // Packed perception features: h2 pp[j] = features (2j, 2j+1); feature
    // index x = k*16 + c (k: 0=ident, 1=sobel-z, 2=sobel-y, 3=sobel-x).
    h2 pp[32];
    float pf0 = 0.f, pf1 = 0.f, pf2 = 0.f, pf3 = 0.f; // even-channel carry
    float amax = -3.0e38f;

#pragma unroll
    for (int g = 0; g < 2; ++g) {
        const float* sg = sb + (size_t)(g * 8) * G3;

        if (g) __syncthreads(); // previous group's stencil reads done (WAR)

        // Bulk-load 8 channels (zero-spill pattern: nothing lives across).
#pragma unroll
        for (int c = 0; c < 8; ++c) {
            tile[c][s0i] = sg[(size_t)c * G3 + vo0];
            tile[c][s1i] = sg[(size_t)c * G3 + vo1];
            if (wr2) tile[c][s2i] = sg[(size_t)c * G3 + vo2];
        }
        __syncthreads();

#pragma unroll
        for (int c = 0; c < 8; ++c) {
            const int cg = g * 8 + c;
            const float* buf = tile[c];
            float P0 = 0.f, P2 = 0.f, U0 = 0.f, U2 = 0.f, V0 = 0.f, V2 = 0.f;
            float ctr = 0.f, mx = -3.0e38f;
#pragma unroll
            for (int dz = 0; dz < 3; ++dz) {
                const float gzw = (dz == 1) ? 2.f : 1.f;
#pragma unroll
                for (int dy = 0; dy < 3; ++dy) {
                    const float gyw = (dy == 1) ? 2.f : 1.f;
                    const float* r = buf + cbase + dz * SZ + dy * SY;
                    const float a0 = r[0], a1 = r[1], a2 = r[2];
                    const float rs = a0 + 2.f * a1 + a2;
                    if (dz == 0) P0 += gyw * rs;
                    if (dz == 2) P2 += gyw * rs;
                    if (dy == 0) U0 += gzw * rs;
                    if (dy == 2) U2 += gzw * rs;
                    V0 += gzw * gyw * a0;
                    V2 += gzw * gyw * a2;
                    if (dz == 1 && dy == 1) ctr = a1;
                    if (cg == 3) mx = fmaxf(mx, fmaxf(fmaxf(a0, a1), a2));
                }
            }
            if (cg == 3) amax = mx;

            const float f0 = ctr;
            const float f1 = (P0 - P2) * 0.0625f;
            const float f2 = (U0 - U2) * 0.0625f;
            const float f3 = (V0 - V2) * 0.0625f;

            if (cg & 1) {
                const int j = cg >> 1;
                h2 v;
                v.x = (_Float16)pf0; v.y = (_Float16)f0; pp[j]      = v;
                v.x = (_Float16)pf1; v.y = (_Float16)f1; pp[8 + j]  = v;
                v.x = (_Float16)pf2; v.y = (_Float16)f2; pp[16 + j] = v;
                v.x = (_Float16)pf3; v.y = (_Float16)f3; pp[24 + j] = v;
            } else {
                pf0 = f0; pf1 = f1; pf2 = f2; pf3 = f3;
            }
        }
    }

    // All waves finished reading the tile; X/H panels may now overwrite it.
    __syncthreads();

    // Pre-alive (own voxel = lane index within wave); used via shuffle below.
    const float pre = (amax > 0.1f) ? 1.f : 0.f;

    // =================== MFMA MLP (wave-private) ===================
    const int lane = tid & 63;
    const int w    = tid >> 6;       // wave = z-slice; gz_wave = z0 + w
    const int l15  = lane & 15;
    const int lg   = lane >> 4;      // lane group 0..3
    char* xw = smem + w * XWAVE;

    // --- write X-panel: row v = lane (this thread's voxel), 64 f16 ---
#pragma unroll
    for (int q = 0; q < 8; ++q) {
        uint4 t;
        t.x = __builtin_bit_cast(unsigned, pp[4 * q]);
        t.y = __builtin_bit_cast(unsigned, pp[4 * q + 1]);
        t.z = __builtin_bit_cast(unsigned, pp[4 * q + 2]);
        t.w = __builtin_bit_cast(unsigned, pp[4 * q + 3]);
        *(uint4*)(xw + lane * XROW + q * 16) = t;
    }

    // --- load B1 fragments (X^T): B[k][v], lane: k=lg*8+j, v=nt*16+l15 ---
    f16x8 bfr[8]; // [kt*4 + nt]
#pragma unroll
    for (int kt = 0; kt < 2; ++kt)
#pragma unroll
        for (int nt = 0; nt < 4; ++nt)
            bfr[kt * 4 + nt] = *(const f16x8*)(xw + (nt * 16 + l15) * XROW + kt * 64 + lg * 16);

    const f16x8* a1 = ((const f16x8*)a1p) + lane;
    const f16x8* a2 = ((const f16x8*)a2p) + lane;

    f32x4 acc2[4];
#pragma unroll
    for (int nt = 0; nt < 4; ++nt) acc2[nt] = (f32x4){0.f, 0.f, 0.f, 0.f};

    // --- interleaved GEMM1/GEMM2 per 32-row hidden block ---
#pragma unroll 1
    for (int kt2 = 0; kt2 < 3; ++kt2) {
#pragma unroll
        for (int mtsub = 0; mtsub < 2; ++mtsub) {
            const int mt = kt2 * 2 + mtsub;
            const f16x8 a_0 = a1[(mt * 2 + 0) * 64];
            const f16x8 a_1 = a1[(mt * 2 + 1) * 64];
            const f32x4 bias = *(const f32x4*)(b1 + mt * 16 + lg * 4);
#pragma unroll
            for (int nt = 0; nt < 4; ++nt) {
                f32x4 acc = (f32x4){0.f, 0.f, 0.f, 0.f};
                acc = mfma16(a_0, bfr[nt],     acc);
                acc = mfma16(a_1, bfr[4 + nt], acc);
                f16x4 hv;
                hv[0] = (_Float16)fmaxf(acc[0] + bias[0], 0.f);
                hv[1] = (_Float16)fmaxf(acc[1] + bias[1], 0.f);
                hv[2] = (_Float16)fmaxf(acc[2] + bias[2], 0.f);
                hv[3] = (_Float16)fmaxf(acc[3] + bias[3], 0.f);
                *(f16x4*)(xw + (nt * 16 + l15) * HROW + mtsub * 32 + lg * 8) = hv;
            }
        }
        const f16x8 a2f = a2[kt2 * 64];
#pragma unroll
        for (int nt = 0; nt < 4; ++nt) {
            const f16x8 b2 = *(const f16x8*)(xw + (nt * 16 + l15) * HROW + lg * 16);
            acc2[nt] = mfma16(a2f, b2, acc2[nt]);
        }
    }

    // --- epilogue: lane holds delta for c = lg*4+r, v = nt*16+l15 ---
    float* ob = out + (size_t)n * C * G3;
    float* ac = acopy + (size_t)n * G3;
#pragma unroll
    for (int nt = 0; nt < 4; ++nt) {
        const int vv = nt * 16 + l15;
        const float prev = __shfl(pre, vv, 64); // pre of voxel vv (lane vv)
        const int vx = vv & 7, vy = vv >> 3;
        const size_t vo = (size_t)(z0 + w) * (G * G) + (size_t)(y0 + vy) * G + (x0 + vx);
        const float ru = rand_u[(size_t)n * G3 + vo];
        const float m = (ru < 0.5f) ? 1.f : 0.f;
#pragma unroll
        for (int r = 0; r < 4; ++r) {
            const int c = lg * 4 + r;
            const float s0 = sb[(size_t)c * G3 + vo];
            const float nv = fmaf(acc2[nt][r], m, s0);
            if (r == 3 && lg == 0) ac[vo] = nv; // c==3: UNMASKED new alpha
            ob[(size_t)c * G3 + vo] = nv * prev;
        }
    }
}

// ---------------------------------------------------------------------------
// Pass 2 (fused): post-alive pooling on the unmasked new alpha (acopy,
// written by nca_update, read-only here) -> zero out dead voxels only.
// Alive voxels (the overwhelming majority for this data distribution:
// 27-point max of ~N(0,1) alpha > 0.1) touch NO out traffic at all --
// multiplying by 1 is a no-op. Bit-exact vs out *= mask.
// ---------------------------------------------------------------------------
__global__ __launch_bounds__(256)
void nca_post(const float* __restrict__ acopy, float* __restrict__ out)
{
    const int idx = blockIdx.x * 256 + threadIdx.x; // over NBATCH*G3
    const int n = idx >> 18;
    const int v = idx & (G3 - 1);
    const int x = v & 63, y = (v >> 6) & 63, z = v >> 12;
    const float* ab = acopy + (size_t)n * G3;
    float mx = -3.0e38f;
#pragma unroll
    for (int dz = -1; dz <= 1; ++dz) {
        const int zz = min(max(z + dz, 0), G - 1);
#pragma unroll
        for (int dy = -1; dy <= 1; ++dy) {
            const int yy = min(max(y + dy, 0), G - 1);
            const int xm = max(x - 1, 0), xp = min(x + 1, G - 1);
            const float* row = ab + (size_t)zz * (G * G) + (size_t)yy * G;
            mx = fmaxf(mx, fmaxf(fmaxf(row[xm], row[x]), row[xp]));
        }
    }
    if (mx > 0.1f) return; // alive: out already holds new_state * pre
    float* ob = out + (size_t)n * C * G3 + v;
#pragma unroll
    for (int c = 0; c < C; ++c) ob[(size_t)c * G3] = 0.f;
}

extern "C" void kernel_launch(void* const* d_in, const int* in_sizes, int n_in,
                              void* d_out, int out_size, void* d_ws, size_t ws_size,
                              hipStream_t stream)
{
    const float* state  = (const float*)d_in[0];
    const float* rand_u = (const float*)d_in[1];
    const float* w1     = (const float*)d_in[2];
    const float* b1     = (const float*)d_in[3];
    const float* w2     = (const float*)d_in[4];
    float* out  = (float*)d_out;

    // Workspace: [0,12KB) a1p, [12KB,15KB) a2p, [16KB, 16KB+4MiB) acopy.
    _Float16* a1p  = (_Float16*)d_ws;
    _Float16* a2p  = (_Float16*)((char*)d_ws + 12 * 1024);
    float*    acop = (float*)((char*)d_ws + 16 * 1024);

    nca_packw <<<24, 256, 0, stream>>>(w1, w2, a1p, a2p);
    nca_update<<<NBATCH * 8 * 8 * 16, 256, 0, stream>>>(state, rand_u, a1p, b1, a2p, out, acop);
    nca_post  <<<(NBATCH * G3) / 256, 256, 0, stream>>>(acop, out);
}

// Round 15
// 133.909 us; speedup vs baseline: 2.1473x; 1.3276x over previous
//
#include <hip/hip_runtime.h>

constexpr int G = 64;
constexpr int C = 16;
constexpr int NBATCH = 4;
constexpr int HID = 96;
constexpr int G3 = G * G * G; // 262144 = 2^18

typedef _Float16 h2    __attribute__((ext_vector_type(2)));
typedef _Float16 f16x4 __attribute__((ext_vector_type(4)));
typedef _Float16 f16x8 __attribute__((ext_vector_type(8)));
typedef float    f32x4 __attribute__((ext_vector_type(4)));

__device__ __forceinline__ f32x4 mfma16(f16x8 a, f16x8 b, f32x4 c) {
    return __builtin_amdgcn_mfma_f32_16x16x32_f16(a, b, c, 0, 0, 0);
}

#if __has_builtin(__builtin_amdgcn_global_load_lds)
#define HAS_GLL 1
__device__ __forceinline__ void gload_lds(const float* g, float* l) {
    __builtin_amdgcn_global_load_lds(
        (const __attribute__((address_space(1))) void*)g,
        (__attribute__((address_space(3))) void*)l, 4, 0, 0);
}
#else
#define HAS_GLL 0
#endif

// ---------------------------------------------------------------------------
// Pass 0: pack W1 (96x64) and W2 (16x96) into MFMA A-fragment order (f16).
// A-frag for mfma_f32_16x16x32_f16: lane l holds A[row = l%16][k = (l/16)*8+j],
// j=0..7 (16B contiguous per lane). (Layout verified by R11: absmax 0.03125.)
// ---------------------------------------------------------------------------
__global__ __launch_bounds__(256)
void nca_packw(const float* __restrict__ w1, const float* __restrict__ w2,
               _Float16* __restrict__ a1p, _Float16* __restrict__ a2p)
{
    const int i = blockIdx.x * 256 + threadIdx.x; // 0..6143
    {
        const int j = i & 7, lane = (i >> 3) & 63, f = i >> 9; // f = mt*2+kt
        const int mt = f >> 1, kt = f & 1;
        const int y = mt * 16 + (lane & 15);
        const int x = kt * 32 + ((lane >> 4) << 3) + j;
        a1p[i] = (_Float16)w1[y * 64 + x];
    }
    if (i < 3 * 512) {
        const int j = i & 7, lane = (i >> 3) & 63, kt2 = i >> 9;
        const int c = lane & 15;
        const int y = kt2 * 32 + ((lane >> 4) << 3) + j;
        a2p[i] = (_Float16)w2[c * HID + y];
    }
}

// ---------------------------------------------------------------------------
// Pass 1: perception + MFMA MLP + pre-alive fold-in.
//
// R15: async double-buffered halo staging via global_load_lds.
// R14 exposed TWO serial HBM-latency rounds per block (load->barrier->
// compute, twice) with only 2 blocks/CU to cover them (occ 22%, all pipes
// <25% busy). Register-prefetch across the stencil is the proven R2-R6
// spill trap; global_load_lds costs ZERO VGPRs: per-lane global source
// (edge-clamped gather is fine) + lane-linear LDS dest. The halo now lives
// in linear j-order (j = lz*100 + ly*10 + lx, 600 elems/channel) so wave w
// slot k writes LDS[64w + 256k + lane] -- exactly the HW pattern. Pipeline:
//   issue ch0-7 -> buf0; barrier(drains);
//   issue ch8-15 -> buf1; stencil ch0-7; barrier(drains buf1); stencil ch8-15
// Group-1's HBM latency hides under group-0's ~2500-cycle stencil. 4
// barriers -> 3; staging VALU (load+write pairs) -> 1 instr. rand_u
// prefetched before the GEMM. X/H panels alias buf0/1 after the stencil.
// Invariant: WRITE_SIZE 69632 KB (zero spill); cap via (256,2).
// ---------------------------------------------------------------------------
constexpr int HALO_N = 600;       // 10*10*6, linear per channel
constexpr int BUF_F  = 8 * HALO_N;// 4800 floats per group buffer
constexpr int XROW = 144;         // X-panel row stride (bytes)
constexpr int HROW = 80;          // H row stride (bytes)
constexpr int XWAVE = 64 * XROW;  // 9216 B per wave

__global__ __launch_bounds__(256, 2)
void nca_update(const float* __restrict__ state, const float* __restrict__ rand_u,
                const _Float16* __restrict__ a1p, const float* __restrict__ b1,
                const _Float16* __restrict__ a2p,
                float* __restrict__ out, float* __restrict__ acopy)
{
    // 2 x 4800 floats (stencil) = 38400 B; GEMM panels (4 x 9216 = 36864 B)
    // alias the same region after the post-stencil barrier.
    __shared__ __align__(16) char smem[2 * BUF_F * 4];
    float* buf0 = (float*)smem;
    float* buf1 = buf0 + BUF_F;

    const int tid = threadIdx.x;
    const int bid = blockIdx.x;
    const int bx = bid & 7, by = (bid >> 3) & 7, bz = (bid >> 6) & 15, n = bid >> 10;
    const int x0 = bx * 8, y0 = by * 8, z0 = bz * 4;
    const float* sb = state + (size_t)n * C * G3;

    // --- halo source offsets, linear j-order (identical every channel) ---
    int vo0, vo1, vo2;
    {
        const int j = tid;
        const int lx = j % 10, t = j / 10, ly = t % 10, lz = t / 10;
        vo0 = min(max(z0 + lz - 1, 0), G - 1) * (G * G)
            + min(max(y0 + ly - 1, 0), G - 1) * G
            + min(max(x0 + lx - 1, 0), G - 1);
    }
    {
        const int j = tid + 256;
        const int lx = j % 10, t = j / 10, ly = t % 10, lz = t / 10;
        vo1 = min(max(z0 + lz - 1, 0), G - 1) * (G * G)
            + min(max(y0 + ly - 1, 0), G - 1) * G
            + min(max(x0 + lx - 1, 0), G - 1);
    }
    const bool act2 = (tid + 512 < HALO_N);
    {
        const int j = min(tid + 512, HALO_N - 1);
        const int lx = j % 10, t = j / 10, ly = t % 10, lz = t / 10;
        vo2 = min(max(z0 + lz - 1, 0), G - 1) * (G * G)
            + min(max(y0 + ly - 1, 0), G - 1) * G
            + min(max(x0 + lx - 1, 0), G - 1);
    }
    const int wbase = tid & ~63; // wave-uniform LDS slot base

    const int lxl = (tid & 7) + 1, lyl = ((tid >> 3) & 7) + 1, lzl = (tid >> 6) + 1; // lzl 1..4
    const int cbase = (lzl - 1) * 100 + (lyl - 1) * 10 + (lxl - 1);

#if HAS_GLL
    // --- issue group 0 (ch 0-7) -> buf0, async, zero VGPR ---
#pragma unroll
    for (int c = 0; c < 8; ++c) {
        const float* gc = sb + (size_t)c * G3;
        gload_lds(gc + vo0, buf0 + c * HALO_N + wbase);
        gload_lds(gc + vo1, buf0 + c * HALO_N + 256 + wbase);
        if (act2) gload_lds(gc + vo2, buf0 + c * HALO_N + 512 + wbase);
    }
    __syncthreads(); // drains vmcnt -> buf0 complete

    // --- issue group 1 (ch 8-15) -> buf1; latency hides under stencil g0 ---
#pragma unroll
    for (int c = 0; c < 8; ++c) {
        const float* gc = sb + (size_t)(8 + c) * G3;
        gload_lds(gc + vo0, buf1 + c * HALO_N + wbase);
        gload_lds(gc + vo1, buf1 + c * HALO_N + 256 + wbase);
        if (act2) gload_lds(gc + vo2, buf1 + c * HALO_N + 512 + wbase);
    }
#else
    // Fallback: synchronous staging (correct, no overlap).
#pragma unroll
    for (int c = 0; c < 8; ++c) {
        const float* gc = sb + (size_t)c * G3;
        buf0[c * HALO_N + tid] = gc[vo0];
        buf0[c * HALO_N + 256 + tid] = gc[vo1];
        if (act2) buf0[c * HALO_N + 512 + tid] = gc[vo2];
    }
    __syncthreads();
#pragma unroll
    for (int c = 0; c < 8; ++c) {
        const float* gc = sb + (size_t)(8 + c) * G3;
        buf1[c * HALO_N + tid] = gc[vo0];
        buf1[c * HALO_N + 256 + tid] = gc[vo1];
        if (act2) buf1[c * HALO_N + 512 + tid] = gc[vo2];
    }
#endif

    // Packed perception features: h2 pp[j] = features (2j, 2j+1); feature
    // index x = k*16 + c (k: 0=ident, 1=sobel-z, 2=sobel-y, 3=sobel-x).
    h2 pp[32];
    float pf0 = 0.f, pf1 = 0.f, pf2 = 0.f, pf3 = 0.f; // even-channel carry
    float amax = -3.0e38f;

#pragma unroll
    for (int g = 0; g < 2; ++g) {
        const float* bb = g ? buf1 : buf0;
        if (g) __syncthreads(); // drains buf1's loads (issued pre-stencil-g0)

#pragma unroll
        for (int c = 0; c < 8; ++c) {
            const int cg = g * 8 + c;
            const float* buf = bb + c * HALO_N;
            float P0 = 0.f, P2 = 0.f, U0 = 0.f, U2 = 0.f, V0 = 0.f, V2 = 0.f;
            float ctr = 0.f, mx = -3.0e38f;
#pragma unroll
            for (int dz = 0; dz < 3; ++dz) {
                const float gzw = (dz == 1) ? 2.f : 1.f;
#pragma unroll
                for (int dy = 0; dy < 3; ++dy) {
                    const float gyw = (dy == 1) ? 2.f : 1.f;
                    const float* r = buf + cbase + dz * 100 + dy * 10;
                    const float a0 = r[0], a1 = r[1], a2 = r[2];
                    const float rs = a0 + 2.f * a1 + a2;
                    if (dz == 0) P0 += gyw * rs;
                    if (dz == 2) P2 += gyw * rs;
                    if (dy == 0) U0 += gzw * rs;
                    if (dy == 2) U2 += gzw * rs;
                    V0 += gzw * gyw * a0;
                    V2 += gzw * gyw * a2;
                    if (dz == 1 && dy == 1) ctr = a1;
                    if (cg == 3) mx = fmaxf(mx, fmaxf(fmaxf(a0, a1), a2));
                }
            }
            if (cg == 3) amax = mx;

            const float f0 = ctr;
            const float f1 = (P0 - P2) * 0.0625f;
            const float f2 = (U0 - U2) * 0.0625f;
            const float f3 = (V0 - V2) * 0.0625f;

            if (cg & 1) {
                const int j = cg >> 1;
                h2 v;
                v.x = (_Float16)pf0; v.y = (_Float16)f0; pp[j]      = v;
                v.x = (_Float16)pf1; v.y = (_Float16)f1; pp[8 + j]  = v;
                v.x = (_Float16)pf2; v.y = (_Float16)f2; pp[16 + j] = v;
                v.x = (_Float16)pf3; v.y = (_Float16)f3; pp[24 + j] = v;
            } else {
                pf0 = f0; pf1 = f1; pf2 = f2; pf3 = f3;
            }
        }
    }

    // All waves finished reading the buffers; X/H panels may overwrite.
    __syncthreads();

    // Pre-alive (own voxel = lane index within wave); used via shuffle below.
    const float pre = (amax > 0.1f) ? 1.f : 0.f;

    // =================== MFMA MLP (wave-private) ===================
    const int lane = tid & 63;
    const int w    = tid >> 6;       // wave = z-slice; gz_wave = z0 + w
    const int l15  = lane & 15;
    const int lg   = lane >> 4;      // lane group 0..3
    char* xw = smem + w * XWAVE;

    // --- write X-panel: row v = lane (this thread's voxel), 64 f16 ---
#pragma unroll
    for (int q = 0; q < 8; ++q) {
        uint4 t;
        t.x = __builtin_bit_cast(unsigned, pp[4 * q]);
        t.y = __builtin_bit_cast(unsigned, pp[4 * q + 1]);
        t.z = __builtin_bit_cast(unsigned, pp[4 * q + 2]);
        t.w = __builtin_bit_cast(unsigned, pp[4 * q + 3]);
        *(uint4*)(xw + lane * XROW + q * 16) = t;
    }

    // rand prefetch: issued now, consumed after the GEMMs (latency hidden).
    float rus[4];
#pragma unroll
    for (int nt = 0; nt < 4; ++nt) {
        const int vv = nt * 16 + l15;
        const size_t vo = (size_t)(z0 + w) * (G * G)
                        + (size_t)(y0 + (vv >> 3)) * G + (x0 + (vv & 7));
        rus[nt] = rand_u[(size_t)n * G3 + vo];
    }

    // --- load B1 fragments (X^T): B[k][v], lane: k=lg*8+j, v=nt*16+l15 ---
    f16x8 bfr[8]; // [kt*4 + nt]
#pragma unroll
    for (int kt = 0; kt < 2; ++kt)
#pragma unroll
        for (int nt = 0; nt < 4; ++nt)
            bfr[kt * 4 + nt] = *(const f16x8*)(xw + (nt * 16 + l15) * XROW + kt * 64 + lg * 16);

    const f16x8* a1 = ((const f16x8*)a1p) + lane;
    const f16x8* a2 = ((const f16x8*)a2p) + lane;

    f32x4 acc2[4];
#pragma unroll
    for (int nt = 0; nt < 4; ++nt) acc2[nt] = (f32x4){0.f, 0.f, 0.f, 0.f};

    // --- interleaved GEMM1/GEMM2 per 32-row hidden block ---
#pragma unroll 1
    for (int kt2 = 0; kt2 < 3; ++kt2) {
#pragma unroll
        for (int mtsub = 0; mtsub < 2; ++mtsub) {
            const int mt = kt2 * 2 + mtsub;
            const f16x8 a_0 = a1[(mt * 2 + 0) * 64];
            const f16x8 a_1 = a1[(mt * 2 + 1) * 64];
            const f32x4 bias = *(const f32x4*)(b1 + mt * 16 + lg * 4);
#pragma unroll
            for (int nt = 0; nt < 4; ++nt) {
                f32x4 acc = (f32x4){0.f, 0.f, 0.f, 0.f};
                acc = mfma16(a_0, bfr[nt],     acc);
                acc = mfma16(a_1, bfr[4 + nt], acc);
                f16x4 hv;
                hv[0] = (_Float16)fmaxf(acc[0] + bias[0], 0.f);
                hv[1] = (_Float16)fmaxf(acc[1] + bias[1], 0.f);
                hv[2] = (_Float16)fmaxf(acc[2] + bias[2], 0.f);
                hv[3] = (_Float16)fmaxf(acc[3] + bias[3], 0.f);
                *(f16x4*)(xw + (nt * 16 + l15) * HROW + mtsub * 32 + lg * 8) = hv;
            }
        }
        const f16x8 a2f = a2[kt2 * 64];
#pragma unroll
        for (int nt = 0; nt < 4; ++nt) {
            const f16x8 b2 = *(const f16x8*)(xw + (nt * 16 + l15) * HROW + lg * 16);
            acc2[nt] = mfma16(a2f, b2, acc2[nt]);
        }
    }

    // --- epilogue: lane holds delta for c = lg*4+r, v = nt*16+l15 ---
    float* ob = out + (size_t)n * C * G3;
    float* ac = acopy + (size_t)n * G3;
#pragma unroll
    for (int nt = 0; nt < 4; ++nt) {
        const int vv = nt * 16 + l15;
        const float prev = __shfl(pre, vv, 64); // pre of voxel vv (lane vv)
        const int vx = vv & 7, vy = vv >> 3;
        const size_t vo = (size_t)(z0 + w) * (G * G) + (size_t)(y0 + vy) * G + (x0 + vx);
        const float m = (rus[nt] < 0.5f) ? 1.f : 0.f;
#pragma unroll
        for (int r = 0; r < 4; ++r) {
            const int c = lg * 4 + r;
            const float s0 = sb[(size_t)c * G3 + vo];
            const float nv = fmaf(acc2[nt][r], m, s0);
            if (r == 3 && lg == 0) ac[vo] = nv; // c==3: UNMASKED new alpha
            ob[(size_t)c * G3 + vo] = nv * prev;
        }
    }
}

// ---------------------------------------------------------------------------
// Pass 2 (fused): post-alive pooling on the unmasked new alpha (acopy) ->
// zero out dead voxels only. Alive voxels (overwhelming majority) touch no
// out traffic: multiplying by 1 is a no-op. Bit-exact vs out *= mask.
// ---------------------------------------------------------------------------
__global__ __launch_bounds__(256)
void nca_post(const float* __restrict__ acopy, float* __restrict__ out)
{
    const int idx = blockIdx.x * 256 + threadIdx.x; // over NBATCH*G3
    const int n = idx >> 18;
    const int v = idx & (G3 - 1);
    const int x = v & 63, y = (v >> 6) & 63, z = v >> 12;
    const float* ab = acopy + (size_t)n * G3;
    float mx = -3.0e38f;
#pragma unroll
    for (int dz = -1; dz <= 1; ++dz) {
        const int zz = min(max(z + dz, 0), G - 1);
#pragma unroll
        for (int dy = -1; dy <= 1; ++dy) {
            const int yy = min(max(y + dy, 0), G - 1);
            const int xm = max(x - 1, 0), xp = min(x + 1, G - 1);
            const float* row = ab + (size_t)zz * (G * G) + (size_t)yy * G;
            mx = fmaxf(mx, fmaxf(fmaxf(row[xm], row[x]), row[xp]));
        }
    }
    if (mx > 0.1f) return; // alive: out already holds new_state * pre
    float* ob = out + (size_t)n * C * G3 + v;
#pragma unroll
    for (int c = 0; c < C; ++c) ob[(size_t)c * G3] = 0.f;
}

extern "C" void kernel_launch(void* const* d_in, const int* in_sizes, int n_in,
                              void* d_out, int out_size, void* d_ws, size_t ws_size,
                              hipStream_t stream)
{
    const float* state  = (const float*)d_in[0];
    const float* rand_u = (const float*)d_in[1];
    const float* w1     = (const float*)d_in[2];
    const float* b1     = (const float*)d_in[3];
    const float* w2     = (const float*)d_in[4];
    float* out  = (float*)d_out;

    // Workspace: [0,12KB) a1p, [12KB,15KB) a2p, [16KB, 16KB+4MiB) acopy.
    _Float16* a1p  = (_Float16*)d_ws;
    _Float16* a2p  = (_Float16*)((char*)d_ws + 12 * 1024);
    float*    acop = (float*)((char*)d_ws + 16 * 1024);

    nca_packw <<<24, 256, 0, stream>>>(w1, w2, a1p, a2p);
    nca_update<<<NBATCH * 8 * 8 * 16, 256, 0, stream>>>(state, rand_u, a1p, b1, a2p, out, acop);
    nca_post  <<<(NBATCH * G3) / 256, 256, 0, stream>>>(acop, out);
}

// Round 16
// 110.163 us; speedup vs baseline: 2.6102x; 1.2156x over previous
//
#include <hip/hip_runtime.h>

constexpr int G = 64;
constexpr int C = 16;
constexpr int NBATCH = 4;
constexpr int HID = 96;
constexpr int G3 = G * G * G; // 262144 = 2^18

typedef _Float16 h2    __attribute__((ext_vector_type(2)));
typedef _Float16 f16x4 __attribute__((ext_vector_type(4)));
typedef _Float16 f16x8 __attribute__((ext_vector_type(8)));
typedef float    f32x4 __attribute__((ext_vector_type(4)));

__device__ __forceinline__ f32x4 mfma16(f16x8 a, f16x8 b, f32x4 c) {
    return __builtin_amdgcn_mfma_f32_16x16x32_f16(a, b, c, 0, 0, 0);
}

#if __has_builtin(__builtin_amdgcn_global_load_lds)
#define HAS_GLL 1
__device__ __forceinline__ void gload_lds(const float* g, float* l) {
    __builtin_amdgcn_global_load_lds(
        (const __attribute__((address_space(1))) void*)g,
        (__attribute__((address_space(3))) void*)l, 4, 0, 0);
}
#else
#define HAS_GLL 0
#endif

// ---------------------------------------------------------------------------
// Pass 0: pack W1 (96x64) and W2 (16x96) into MFMA A-fragment order (f16).
// A-frag for mfma_f32_16x16x32_f16: lane l holds A[row = l%16][k = (l/16)*8+j],
// j=0..7 (16B contiguous per lane). (Layout verified by R11: absmax 0.03125.)
// ---------------------------------------------------------------------------
__global__ __launch_bounds__(256)
void nca_packw(const float* __restrict__ w1, const float* __restrict__ w2,
               _Float16* __restrict__ a1p, _Float16* __restrict__ a2p)
{
    const int i = blockIdx.x * 256 + threadIdx.x; // 0..6143
    {
        const int j = i & 7, lane = (i >> 3) & 63, f = i >> 9; // f = mt*2+kt
        const int mt = f >> 1, kt = f & 1;
        const int y = mt * 16 + (lane & 15);
        const int x = kt * 32 + ((lane >> 4) << 3) + j;
        a1p[i] = (_Float16)w1[y * 64 + x];
    }
    if (i < 3 * 512) {
        const int j = i & 7, lane = (i >> 3) & 63, kt2 = i >> 9;
        const int c = lane & 15;
        const int y = kt2 * 32 + ((lane >> 4) << 3) + j;
        a2p[i] = (_Float16)w2[c * HID + y];
    }
}

// ---------------------------------------------------------------------------
// Pass 1: perception + MFMA MLP + pre-alive fold-in.
//
// R16 = R15 + voxel-major epilogue via LDS delta-transpose.
// R15's epilogue left voxels lane-distributed, forcing (a) a 64 MB s0
// re-read of state (L2-evicted by epilogue time -> real HBM traffic;
// FETCH 316 vs ~250 MB ideal) and (b) 4x-duplicated rand loads (all 4
// lane-groups fetch the same voxel's ru). Fix: after GEMM2, each lane
// writes its acc2 into the (dead) H panel keyed by voxel row; reads back
// its OWN voxel's 16 channels (4x ds_write_b128 + 4x ds_read_b128,
// wave-private, in-order, no barrier). Then: s0 = ctrf[c] (exact fp32
// centers captured in registers during the stencil -- bit-identical to
// the re-read), own ru (1 load), own pre (no shuffle).
// Register budget: R15's base was 64; +ctrf[16] + transpose temps ~= 84.
// __launch_bounds__(256,3) caps at 85 -> guaranteed 3 waves/SIMD.
// Invariant: WRITE_SIZE 69632 KB (spill detector; if fired, revert cap).
// ---------------------------------------------------------------------------
constexpr int HALO_N = 600;       // 10*10*6, linear per channel
constexpr int BUF_F  = 8 * HALO_N;// 4800 floats per group buffer
constexpr int XROW = 144;         // X-panel row stride (bytes)
constexpr int HROW = 80;          // H / delta-transpose row stride (bytes)
constexpr int XWAVE = 64 * XROW;  // 9216 B per wave

__global__ __launch_bounds__(256, 3)
void nca_update(const float* __restrict__ state, const float* __restrict__ rand_u,
                const _Float16* __restrict__ a1p, const float* __restrict__ b1,
                const _Float16* __restrict__ a2p,
                float* __restrict__ out, float* __restrict__ acopy)
{
    // 2 x 4800 floats (stencil) = 38400 B; GEMM panels (4 x 9216 = 36864 B)
    // alias the same region after the post-stencil barrier.
    __shared__ __align__(16) char smem[2 * BUF_F * 4];
    float* buf0 = (float*)smem;
    float* buf1 = buf0 + BUF_F;

    const int tid = threadIdx.x;
    const int bid = blockIdx.x;
    const int bx = bid & 7, by = (bid >> 3) & 7, bz = (bid >> 6) & 15, n = bid >> 10;
    const int x0 = bx * 8, y0 = by * 8, z0 = bz * 4;
    const float* sb = state + (size_t)n * C * G3;

    // --- halo source offsets, linear j-order (identical every channel) ---
    int vo0, vo1, vo2;
    {
        const int j = tid;
        const int lx = j % 10, t = j / 10, ly = t % 10, lz = t / 10;
        vo0 = min(max(z0 + lz - 1, 0), G - 1) * (G * G)
            + min(max(y0 + ly - 1, 0), G - 1) * G
            + min(max(x0 + lx - 1, 0), G - 1);
    }
    {
        const int j = tid + 256;
        const int lx = j % 10, t = j / 10, ly = t % 10, lz = t / 10;
        vo1 = min(max(z0 + lz - 1, 0), G - 1) * (G * G)
            + min(max(y0 + ly - 1, 0), G - 1) * G
            + min(max(x0 + lx - 1, 0), G - 1);
    }
    const bool act2 = (tid + 512 < HALO_N);
    {
        const int j = min(tid + 512, HALO_N - 1);
        const int lx = j % 10, t = j / 10, ly = t % 10, lz = t / 10;
        vo2 = min(max(z0 + lz - 1, 0), G - 1) * (G * G)
            + min(max(y0 + ly - 1, 0), G - 1) * G
            + min(max(x0 + lx - 1, 0), G - 1);
    }
    const int wbase = tid & ~63; // wave-uniform LDS slot base

    // Own voxel (== lane's voxel of wave's z-slice).
    const int lxl = (tid & 7) + 1, lyl = ((tid >> 3) & 7) + 1, lzl = (tid >> 6) + 1;
    const int cbase = (lzl - 1) * 100 + (lyl - 1) * 10 + (lxl - 1);
    const size_t vofs = (size_t)(z0 + lzl - 1) * (G * G)
                      + (size_t)(y0 + lyl - 1) * G + (x0 + lxl - 1);
    const float ru = rand_u[(size_t)n * G3 + vofs]; // own rand, issued early

#if HAS_GLL
    // --- issue group 0 (ch 0-7) -> buf0, async, zero VGPR ---
#pragma unroll
    for (int c = 0; c < 8; ++c) {
        const float* gc = sb + (size_t)c * G3;
        gload_lds(gc + vo0, buf0 + c * HALO_N + wbase);
        gload_lds(gc + vo1, buf0 + c * HALO_N + 256 + wbase);
        if (act2) gload_lds(gc + vo2, buf0 + c * HALO_N + 512 + wbase);
    }
    __syncthreads(); // drains vmcnt -> buf0 complete

    // --- issue group 1 (ch 8-15) -> buf1; latency hides under stencil g0 ---
#pragma unroll
    for (int c = 0; c < 8; ++c) {
        const float* gc = sb + (size_t)(8 + c) * G3;
        gload_lds(gc + vo0, buf1 + c * HALO_N + wbase);
        gload_lds(gc + vo1, buf1 + c * HALO_N + 256 + wbase);
        if (act2) gload_lds(gc + vo2, buf1 + c * HALO_N + 512 + wbase);
    }
#else
    // Fallback: synchronous staging (correct, no overlap).
#pragma unroll
    for (int c = 0; c < 8; ++c) {
        const float* gc = sb + (size_t)c * G3;
        buf0[c * HALO_N + tid] = gc[vo0];
        buf0[c * HALO_N + 256 + tid] = gc[vo1];
        if (act2) buf0[c * HALO_N + 512 + tid] = gc[vo2];
    }
    __syncthreads();
#pragma unroll
    for (int c = 0; c < 8; ++c) {
        const float* gc = sb + (size_t)(8 + c) * G3;
        buf1[c * HALO_N + tid] = gc[vo0];
        buf1[c * HALO_N + 256 + tid] = gc[vo1];
        if (act2) buf1[c * HALO_N + 512 + tid] = gc[vo2];
    }
#endif

    // Packed perception features + exact fp32 centers.
    h2 pp[32];
    float ctrf[C]; // own-voxel centers: exact s0 passthrough, no re-read
    float pf0 = 0.f, pf1 = 0.f, pf2 = 0.f, pf3 = 0.f; // even-channel carry
    float amax = -3.0e38f;

#pragma unroll
    for (int g = 0; g < 2; ++g) {
        const float* bb = g ? buf1 : buf0;
        if (g) __syncthreads(); // drains buf1's loads (issued pre-stencil-g0)

#pragma unroll
        for (int c = 0; c < 8; ++c) {
            const int cg = g * 8 + c;
            const float* buf = bb + c * HALO_N;
            float P0 = 0.f, P2 = 0.f, U0 = 0.f, U2 = 0.f, V0 = 0.f, V2 = 0.f;
            float ctr = 0.f, mx = -3.0e38f;
#pragma unroll
            for (int dz = 0; dz < 3; ++dz) {
                const float gzw = (dz == 1) ? 2.f : 1.f;
#pragma unroll
                for (int dy = 0; dy < 3; ++dy) {
                    const float gyw = (dy == 1) ? 2.f : 1.f;
                    const float* r = buf + cbase + dz * 100 + dy * 10;
                    const float a0 = r[0], a1 = r[1], a2 = r[2];
                    const float rs = a0 + 2.f * a1 + a2;
                    if (dz == 0) P0 += gyw * rs;
                    if (dz == 2) P2 += gyw * rs;
                    if (dy == 0) U0 += gzw * rs;
                    if (dy == 2) U2 += gzw * rs;
                    V0 += gzw * gyw * a0;
                    V2 += gzw * gyw * a2;
                    if (dz == 1 && dy == 1) ctr = a1;
                    if (cg == 3) mx = fmaxf(mx, fmaxf(fmaxf(a0, a1), a2));
                }
            }
            if (cg == 3) amax = mx;
            ctrf[cg] = ctr;

            const float f0 = ctr;
            const float f1 = (P0 - P2) * 0.0625f;
            const float f2 = (U0 - U2) * 0.0625f;
            const float f3 = (V0 - V2) * 0.0625f;

            if (cg & 1) {
                const int j = cg >> 1;
                h2 v;
                v.x = (_Float16)pf0; v.y = (_Float16)f0; pp[j]      = v;
                v.x = (_Float16)pf1; v.y = (_Float16)f1; pp[8 + j]  = v;
                v.x = (_Float16)pf2; v.y = (_Float16)f2; pp[16 + j] = v;
                v.x = (_Float16)pf3; v.y = (_Float16)f3; pp[24 + j] = v;
            } else {
                pf0 = f0; pf1 = f1; pf2 = f2; pf3 = f3;
            }
        }
    }

    // All waves finished reading the buffers; X/H panels may overwrite.
    __syncthreads();

    const float pre = (amax > 0.1f) ? 1.f : 0.f; // own voxel

    // =================== MFMA MLP (wave-private) ===================
    const int lane = tid & 63;
    const int w    = tid >> 6;       // wave = z-slice
    const int l15  = lane & 15;
    const int lg   = lane >> 4;      // lane group 0..3
    char* xw = smem + w * XWAVE;

    // --- write X-panel: row v = lane (this thread's voxel), 64 f16 ---
#pragma unroll
    for (int q = 0; q < 8; ++q) {
        uint4 t;
        t.x = __builtin_bit_cast(unsigned, pp[4 * q]);
        t.y = __builtin_bit_cast(unsigned, pp[4 * q + 1]);
        t.z = __builtin_bit_cast(unsigned, pp[4 * q + 2]);
        t.w = __builtin_bit_cast(unsigned, pp[4 * q + 3]);
        *(uint4*)(xw + lane * XROW + q * 16) = t;
    }

    // --- load B1 fragments (X^T): B[k][v], lane: k=lg*8+j, v=nt*16+l15 ---
    f16x8 bfr[8]; // [kt*4 + nt]
#pragma unroll
    for (int kt = 0; kt < 2; ++kt)
#pragma unroll
        for (int nt = 0; nt < 4; ++nt)
            bfr[kt * 4 + nt] = *(const f16x8*)(xw + (nt * 16 + l15) * XROW + kt * 64 + lg * 16);

    const f16x8* a1 = ((const f16x8*)a1p) + lane;
    const f16x8* a2 = ((const f16x8*)a2p) + lane;

    f32x4 acc2[4];
#pragma unroll
    for (int nt = 0; nt < 4; ++nt) acc2[nt] = (f32x4){0.f, 0.f, 0.f, 0.f};

    // --- interleaved GEMM1/GEMM2 per 32-row hidden block ---
#pragma unroll 1
    for (int kt2 = 0; kt2 < 3; ++kt2) {
#pragma unroll
        for (int mtsub = 0; mtsub < 2; ++mtsub) {
            const int mt = kt2 * 2 + mtsub;
            const f16x8 a_0 = a1[(mt * 2 + 0) * 64];
            const f16x8 a_1 = a1[(mt * 2 + 1) * 64];
            const f32x4 bias = *(const f32x4*)(b1 + mt * 16 + lg * 4);
#pragma unroll
            for (int nt = 0; nt < 4; ++nt) {
                f32x4 acc = (f32x4){0.f, 0.f, 0.f, 0.f};
                acc = mfma16(a_0, bfr[nt],     acc);
                acc = mfma16(a_1, bfr[4 + nt], acc);
                f16x4 hv;
                hv[0] = (_Float16)fmaxf(acc[0] + bias[0], 0.f);
                hv[1] = (_Float16)fmaxf(acc[1] + bias[1], 0.f);
                hv[2] = (_Float16)fmaxf(acc[2] + bias[2], 0.f);
                hv[3] = (_Float16)fmaxf(acc[3] + bias[3], 0.f);
                *(f16x4*)(xw + (nt * 16 + l15) * HROW + mtsub * 32 + lg * 8) = hv;
            }
        }
        const f16x8 a2f = a2[kt2 * 64];
#pragma unroll
        for (int nt = 0; nt < 4; ++nt) {
            const f16x8 b2 = *(const f16x8*)(xw + (nt * 16 + l15) * HROW + lg * 16);
            acc2[nt] = mfma16(a2f, b2, acc2[nt]);
        }
    }

    // --- delta transpose through the (now dead) H panel: row = voxel,
    //     16 ch x 4B per row at stride HROW. Wave-private, in-order.
#pragma unroll
    for (int nt = 0; nt < 4; ++nt) {
        *(f32x4*)(xw + (nt * 16 + l15) * HROW + lg * 16) = acc2[nt];
    }

    // --- epilogue: own voxel, all 16 channels ---
    const float m = (ru < 0.5f) ? 1.f : 0.f;
    float* ob = out + (size_t)n * C * G3;
    float* ac = acopy + (size_t)n * G3;
#pragma unroll
    for (int q = 0; q < 4; ++q) {
        const f32x4 dv = *(const f32x4*)(xw + lane * HROW + q * 16);
#pragma unroll
        for (int r = 0; r < 4; ++r) {
            const int c = q * 4 + r;
            const float nv = fmaf(dv[r], m, ctrf[c]);
            if (c == 3) ac[vofs] = nv; // UNMASKED new alpha
            ob[(size_t)c * G3 + vofs] = nv * pre;
        }
    }
}

// ---------------------------------------------------------------------------
// Pass 2 (fused): post-alive pooling on the unmasked new alpha (acopy) ->
// zero out dead voxels only. Alive voxels (overwhelming majority) touch no
// out traffic: multiplying by 1 is a no-op. Bit-exact vs out *= mask.
// ---------------------------------------------------------------------------
__global__ __launch_bounds__(256)
void nca_post(const float* __restrict__ acopy, float* __restrict__ out)
{
    const int idx = blockIdx.x * 256 + threadIdx.x; // over NBATCH*G3
    const int n = idx >> 18;
    const int v = idx & (G3 - 1);
    const int x = v & 63, y = (v >> 6) & 63, z = v >> 12;
    const float* ab = acopy + (size_t)n * G3;
    float mx = -3.0e38f;
#pragma unroll
    for (int dz = -1; dz <= 1; ++dz) {
        const int zz = min(max(z + dz, 0), G - 1);
#pragma unroll
        for (int dy = -1; dy <= 1; ++dy) {
            const int yy = min(max(y + dy, 0), G - 1);
            const int xm = max(x - 1, 0), xp = min(x + 1, G - 1);
            const float* row = ab + (size_t)zz * (G * G) + (size_t)yy * G;
            mx = fmaxf(mx, fmaxf(fmaxf(row[xm], row[x]), row[xp]));
        }
    }
    if (mx > 0.1f) return; // alive: out already holds new_state * pre
    float* ob = out + (size_t)n * C * G3 + v;
#pragma unroll
    for (int c = 0; c < C; ++c) ob[(size_t)c * G3] = 0.f;
}

extern "C" void kernel_launch(void* const* d_in, const int* in_sizes, int n_in,
                              void* d_out, int out_size, void* d_ws, size_t ws_size,
                              hipStream_t stream)
{
    const float* state  = (const float*)d_in[0];
    const float* rand_u = (const float*)d_in[1];
    const float* w1     = (const float*)d_in[2];
    const float* b1     = (const float*)d_in[3];
    const float* w2     = (const float*)d_in[4];
    float* out  = (float*)d_out;

    // Workspace: [0,12KB) a1p, [12KB,15KB) a2p, [16KB, 16KB+4MiB) acopy.
    _Float16* a1p  = (_Float16*)d_ws;
    _Float16* a2p  = (_Float16*)((char*)d_ws + 12 * 1024);
    float*    acop = (float*)((char*)d_ws + 16 * 1024);

    nca_packw <<<24, 256, 0, stream>>>(w1, w2, a1p, a2p);
    nca_update<<<NBATCH * 8 * 8 * 16, 256, 0, stream>>>(state, rand_u, a1p, b1, a2p, out, acop);
    nca_post  <<<(NBATCH * G3) / 256, 256, 0, stream>>>(acop, out);
}